// Round 3
// baseline (13327.391 us; speedup 1.0000x reference)
//
#include <hip/hip_runtime.h>
#include <cstdint>
#include <cstddef>

#define SEQ   2048
#define BATCH 64
#define HID   512

// ---------------------------------------------------------------------------
// proj GEMM: C[m][n] = sum_k A[m][k] * W[n][k] + bias[n]
// A: [M][512] row-major, W: [512][512] row-major (NT layout -> both row reads)
// BM=128 BN=128 BK=16, 256 threads, per-thread 8 rows x (4+4) cols
// ---------------------------------------------------------------------------
__global__ __launch_bounds__(256)
void proj_gemm(const float* __restrict__ A, const float* __restrict__ W,
               const float* __restrict__ bias, float* __restrict__ C)
{
    __shared__ float As[16][132];   // transposed: As[k][row], pad 132
    __shared__ float Bs[16][132];   // Bs[k][col]
    const int t  = threadIdx.x;
    const int bm = blockIdx.x >> 2;     // 1024 m-tiles
    const int bn = blockIdx.x & 3;      // 4 n-tiles
    const int m0 = bm * 128;
    const int n0 = bn * 128;
    const int tn = t & 15;
    const int tm = t >> 4;

    float acc[8][8];
#pragma unroll
    for (int i = 0; i < 8; ++i)
#pragma unroll
        for (int j = 0; j < 8; ++j) acc[i][j] = 0.f;

    const int lrow = t >> 2;   // 0..63
    const int lk4  = t & 3;    // float4 index within 16-wide k tile

    for (int kk = 0; kk < 512; kk += 16) {
#pragma unroll
        for (int i = 0; i < 2; ++i) {
            const int row = lrow + i * 64;
            float4 va = *(const float4*)&A[(size_t)(m0 + row) * 512 + kk + lk4 * 4];
            As[lk4 * 4 + 0][row] = va.x;
            As[lk4 * 4 + 1][row] = va.y;
            As[lk4 * 4 + 2][row] = va.z;
            As[lk4 * 4 + 3][row] = va.w;
            float4 vb = *(const float4*)&W[(size_t)(n0 + row) * 512 + kk + lk4 * 4];
            Bs[lk4 * 4 + 0][row] = vb.x;
            Bs[lk4 * 4 + 1][row] = vb.y;
            Bs[lk4 * 4 + 2][row] = vb.z;
            Bs[lk4 * 4 + 3][row] = vb.w;
        }
        __syncthreads();
#pragma unroll
        for (int k = 0; k < 16; ++k) {
            float4 a0 = *(const float4*)&As[k][tm * 8];
            float4 a1 = *(const float4*)&As[k][tm * 8 + 4];
            float4 b0 = *(const float4*)&Bs[k][tn * 4];
            float4 b1 = *(const float4*)&Bs[k][64 + tn * 4];
            float ar[8] = {a0.x, a0.y, a0.z, a0.w, a1.x, a1.y, a1.z, a1.w};
            float bc[8] = {b0.x, b0.y, b0.z, b0.w, b1.x, b1.y, b1.z, b1.w};
#pragma unroll
            for (int i = 0; i < 8; ++i)
#pragma unroll
                for (int j = 0; j < 8; ++j)
                    acc[i][j] = fmaf(ar[i], bc[j], acc[i][j]);
        }
        __syncthreads();
    }

    float4 bv0 = *(const float4*)&bias[n0 + tn * 4];
    float4 bv1 = *(const float4*)&bias[n0 + 64 + tn * 4];
    const float bb[8] = {bv0.x, bv0.y, bv0.z, bv0.w, bv1.x, bv1.y, bv1.z, bv1.w};
#pragma unroll
    for (int i = 0; i < 8; ++i) {
        const size_t rowoff = (size_t)(m0 + tm * 8 + i) * 512 + n0;
        float4 o0, o1;
        o0.x = acc[i][0] + bb[0]; o0.y = acc[i][1] + bb[1];
        o0.z = acc[i][2] + bb[2]; o0.w = acc[i][3] + bb[3];
        o1.x = acc[i][4] + bb[4]; o1.y = acc[i][5] + bb[5];
        o1.z = acc[i][6] + bb[6]; o1.w = acc[i][7] + bb[7];
        *(float4*)&C[rowoff + tn * 4] = o0;
        *(float4*)&C[rowoff + 64 + tn * 4] = o1;
    }
}

// ---------------------------------------------------------------------------
// Recurrent scan. Persistent cooperative kernel, grid = 256 WGs.
// Group g (32 groups) = batch pair (2g, 2g+1); slice s (8 per group) owns
// rows [64s, 64s+64) of W_hh, held ENTIRELY IN VGPRs:
//   thread (r = t&63, wave w = t>>6) holds W[base+r][w*128 .. w*128+127]
//   as 32 float4s (128 VGPRs). LDS is used only for (a) broadcast-staging
//   the polled h (all-lane-same-address ds_read_b128 -> conflict-free) and
//   (b) a 512-float cross-wave partial reduce.
// Sync: tagged-u64 relaxed agent-scope atomics with parity double-buffer
// (see round-2 proof; unchanged protocol, remapped thread->slot for
// coalescing: lane l polls u64 l, l+256, l+512, l+768 of the group's 1024).
// ---------------------------------------------------------------------------
__global__ __launch_bounds__(256)
void rnn_scan(const float* __restrict__ proj, const float* __restrict__ Whh,
              const float* __restrict__ bhh, float* __restrict__ out,
              float* __restrict__ hidden, unsigned long long* __restrict__ hbuf)
{
    __shared__ float4 hS[256];     // [b][128] float4 view of h (2 x 512 f32)
    __shared__ float  part[512];   // [w*2+b][64]

    const int t    = threadIdx.x;
    const int g    = blockIdx.x & 31;
    const int s    = blockIdx.x >> 5;
    const int b0   = g * 2;
    const int base = s * 64;
    const int r    = t & 63;
    const int w    = t >> 6;

    // ---- load W slice into registers (one-time, 128 KB/WG) ----
    float4 Wreg[32];
#pragma unroll
    for (int j = 0; j < 32; ++j)
        Wreg[j] = *(const float4*)&Whh[(size_t)(base + r) * HID + w * 128 + j * 4];

    float breg = 0.f;
    if (t < 128) breg = bhh[base + r];

    float* hF = (float*)hS;

    for (int step = 0; step < SEQ; ++step) {
        // ---- proj prefetch (independent of h) ----
        float pv = 0.f;
        size_t oidx = 0;
        if (t < 128) {
            const int b = t >> 6;
            oidx = (size_t)step * (BATCH * HID) + (size_t)(b0 + b) * HID + base + r;
            pv = proj[oidx];
        }

        // ---- poll 4 coalesced tagged u64 (group's 1024 = 2 batch x 512) ----
        {
            const unsigned long long* src =
                hbuf + (size_t)(step & 1) * (BATCH * HID) + (size_t)b0 * HID + t;
            const unsigned int want = (unsigned int)step;
            float v0 = 0.f, v1 = 0.f, v2 = 0.f, v3 = 0.f;
            bool ok0 = false, ok1 = false, ok2 = false, ok3 = false;
            int spins = 0;
            while (!(ok0 & ok1 & ok2 & ok3)) {
                if (!ok0) {
                    unsigned long long x = __hip_atomic_load(src + 0,   __ATOMIC_RELAXED, __HIP_MEMORY_SCOPE_AGENT);
                    if ((unsigned int)(x >> 32) == want) { v0 = __uint_as_float((unsigned int)x); ok0 = true; }
                }
                if (!ok1) {
                    unsigned long long x = __hip_atomic_load(src + 256, __ATOMIC_RELAXED, __HIP_MEMORY_SCOPE_AGENT);
                    if ((unsigned int)(x >> 32) == want) { v1 = __uint_as_float((unsigned int)x); ok1 = true; }
                }
                if (!ok2) {
                    unsigned long long x = __hip_atomic_load(src + 512, __ATOMIC_RELAXED, __HIP_MEMORY_SCOPE_AGENT);
                    if ((unsigned int)(x >> 32) == want) { v2 = __uint_as_float((unsigned int)x); ok2 = true; }
                }
                if (!ok3) {
                    unsigned long long x = __hip_atomic_load(src + 768, __ATOMIC_RELAXED, __HIP_MEMORY_SCOPE_AGENT);
                    if ((unsigned int)(x >> 32) == want) { v3 = __uint_as_float((unsigned int)x); ok3 = true; }
                }
                if (!(ok0 & ok1 & ok2 & ok3)) {
                    __builtin_amdgcn_s_sleep(1);
                    if (++spins > 4096) {            // hang-proofing only
                        __builtin_amdgcn_fence(__ATOMIC_ACQUIRE, "agent");
                        spins = 0;
                    }
                }
            }
            hF[t]       = v0;
            hF[t + 256] = v1;
            hF[t + 512] = v2;
            hF[t + 768] = v3;
        }
        __syncthreads();   // (A) h staged

        // ---- matvec: W in regs, h broadcast from LDS ----
        // wave w covers k in [w*128, w*128+128) = float4 cols w*32..w*32+31
        float a0e = 0.f, a0o = 0.f, a1e = 0.f, a1o = 0.f;
        const float4* h0p = &hS[w * 32];
        const float4* h1p = &hS[128 + w * 32];
#pragma unroll
        for (int j = 0; j < 32; j += 2) {
            float4 ha = h0p[j];
            float4 hb = h1p[j];
            float4 W0 = Wreg[j];
            a0e = fmaf(W0.x, ha.x, a0e); a0e = fmaf(W0.y, ha.y, a0e);
            a0e = fmaf(W0.z, ha.z, a0e); a0e = fmaf(W0.w, ha.w, a0e);
            a1e = fmaf(W0.x, hb.x, a1e); a1e = fmaf(W0.y, hb.y, a1e);
            a1e = fmaf(W0.z, hb.z, a1e); a1e = fmaf(W0.w, hb.w, a1e);
            float4 hc = h0p[j + 1];
            float4 hd = h1p[j + 1];
            float4 W1 = Wreg[j + 1];
            a0o = fmaf(W1.x, hc.x, a0o); a0o = fmaf(W1.y, hc.y, a0o);
            a0o = fmaf(W1.z, hc.z, a0o); a0o = fmaf(W1.w, hc.w, a0o);
            a1o = fmaf(W1.x, hd.x, a1o); a1o = fmaf(W1.y, hd.y, a1o);
            a1o = fmaf(W1.z, hd.z, a1o); a1o = fmaf(W1.w, hd.w, a1o);
        }
        part[(w * 2 + 0) * 64 + r] = a0e + a0o;
        part[(w * 2 + 1) * 64 + r] = a1e + a1o;
        __syncthreads();   // (B) partials ready

        // ---- reduce 4 wave-partials, add proj + bias, tanh, publish ----
        if (t < 128) {
            const int b = t >> 6;
            const float sum = part[(0 + b) * 64 + r] + part[(2 + b) * 64 + r]
                            + part[(4 + b) * 64 + r] + part[(6 + b) * 64 + r];
            const float hn = tanhf(pv + breg + sum);
            out[oidx] = hn;
            const unsigned long long pk =
                ((unsigned long long)(unsigned int)(step + 1) << 32) |
                (unsigned long long)__float_as_uint(hn);
            __hip_atomic_store(
                &hbuf[(size_t)((step + 1) & 1) * (BATCH * HID)
                      + (size_t)(b0 + b) * HID + base + r],
                pk, __ATOMIC_RELAXED, __HIP_MEMORY_SCOPE_AGENT);
            if (step == SEQ - 1) hidden[(size_t)(b0 + b) * HID + base + r] = hn;
        }
        // no third barrier needed: next step touches hS only after barrier (A),
        // and part only after barrier (A)+compute; reduce reads complete before
        // any thread can pass next step's (A).
    }
}

// ---------------------------------------------------------------------------
extern "C" void kernel_launch(void* const* d_in, const int* in_sizes, int n_in,
                              void* d_out, int out_size, void* d_ws, size_t ws_size,
                              hipStream_t stream)
{
    (void)in_sizes; (void)n_in; (void)out_size; (void)ws_size;

    const float* x    = (const float*)d_in[0];
    const float* Wih0 = (const float*)d_in[1];
    const float* Whh0 = (const float*)d_in[2];
    const float* bih0 = (const float*)d_in[3];
    const float* bhh0 = (const float*)d_in[4];
    const float* Wih1 = (const float*)d_in[5];
    const float* Whh1 = (const float*)d_in[6];
    const float* bih1 = (const float*)d_in[7];
    const float* bhh1 = (const float*)d_in[8];

    float* out1   = (float*)d_out;                        // [S][B][H]
    float* hidden = out1 + (size_t)SEQ * BATCH * HID;     // [2][B][H]

    float* proj = (float*)d_ws;                           // [S][B][H] f32
    unsigned long long* hbufA =
        (unsigned long long*)(proj + (size_t)SEQ * BATCH * HID);  // [2][B][H] u64
    unsigned long long* hbufB = hbufA + (size_t)2 * BATCH * HID;  // [2][B][H] u64

    // zero both layers' tagged h-state buffers (tag 0 == epoch 0, h = 0)
    hipMemsetAsync(hbufA, 0, (size_t)4 * BATCH * HID * sizeof(unsigned long long),
                   stream);

    // ---- layer 0 ----
    proj_gemm<<<dim3(4096), dim3(256), 0, stream>>>(x, Wih0, bih0, proj);
    {
        const float* p = proj; const float* w = Whh0; const float* bb = bhh0;
        float* o = out1; float* hd = hidden; unsigned long long* hb = hbufA;
        void* args[] = {&p, &w, &bb, &o, &hd, &hb};
        hipLaunchCooperativeKernel((const void*)rnn_scan, dim3(256), dim3(256),
                                   args, 0, stream);
    }

    // ---- layer 1 (out0 staged in d_out's out1 region) ----
    proj_gemm<<<dim3(4096), dim3(256), 0, stream>>>(out1, Wih1, bih1, proj);
    {
        const float* p = proj; const float* w = Whh1; const float* bb = bhh1;
        float* o = out1; float* hd = hidden + BATCH * HID; unsigned long long* hb = hbufB;
        void* args[] = {&p, &w, &bb, &o, &hd, &hb};
        hipLaunchCooperativeKernel((const void*)rnn_scan, dim3(256), dim3(256),
                                   args, 0, stream);
    }
}

// Round 4
// 7998.994 us; speedup vs baseline: 1.6661x; 1.6661x over previous
//
#include <hip/hip_runtime.h>
#include <cstdint>
#include <cstddef>

#define SEQ   2048
#define BATCH 64
#define HID   512

// ---------------------------------------------------------------------------
// proj GEMM: C[m][n] = sum_k A[m][k] * W[n][k] + bias[n]
// A: [M][512] row-major, W: [512][512] row-major (NT layout -> both row reads)
// BM=128 BN=128 BK=16, 256 threads, per-thread 8 rows x (4+4) cols
// ---------------------------------------------------------------------------
__global__ __launch_bounds__(256)
void proj_gemm(const float* __restrict__ A, const float* __restrict__ W,
               const float* __restrict__ bias, float* __restrict__ C)
{
    __shared__ float As[16][132];   // transposed: As[k][row], pad 132
    __shared__ float Bs[16][132];   // Bs[k][col]
    const int t  = threadIdx.x;
    const int bm = blockIdx.x >> 2;     // 1024 m-tiles
    const int bn = blockIdx.x & 3;      // 4 n-tiles
    const int m0 = bm * 128;
    const int n0 = bn * 128;
    const int tn = t & 15;
    const int tm = t >> 4;

    float acc[8][8];
#pragma unroll
    for (int i = 0; i < 8; ++i)
#pragma unroll
        for (int j = 0; j < 8; ++j) acc[i][j] = 0.f;

    const int lrow = t >> 2;   // 0..63
    const int lk4  = t & 3;    // float4 index within 16-wide k tile

    for (int kk = 0; kk < 512; kk += 16) {
#pragma unroll
        for (int i = 0; i < 2; ++i) {
            const int row = lrow + i * 64;
            float4 va = *(const float4*)&A[(size_t)(m0 + row) * 512 + kk + lk4 * 4];
            As[lk4 * 4 + 0][row] = va.x;
            As[lk4 * 4 + 1][row] = va.y;
            As[lk4 * 4 + 2][row] = va.z;
            As[lk4 * 4 + 3][row] = va.w;
            float4 vb = *(const float4*)&W[(size_t)(n0 + row) * 512 + kk + lk4 * 4];
            Bs[lk4 * 4 + 0][row] = vb.x;
            Bs[lk4 * 4 + 1][row] = vb.y;
            Bs[lk4 * 4 + 2][row] = vb.z;
            Bs[lk4 * 4 + 3][row] = vb.w;
        }
        __syncthreads();
#pragma unroll
        for (int k = 0; k < 16; ++k) {
            float4 a0 = *(const float4*)&As[k][tm * 8];
            float4 a1 = *(const float4*)&As[k][tm * 8 + 4];
            float4 b0 = *(const float4*)&Bs[k][tn * 4];
            float4 b1 = *(const float4*)&Bs[k][64 + tn * 4];
            float ar[8] = {a0.x, a0.y, a0.z, a0.w, a1.x, a1.y, a1.z, a1.w};
            float bc[8] = {b0.x, b0.y, b0.z, b0.w, b1.x, b1.y, b1.z, b1.w};
#pragma unroll
            for (int i = 0; i < 8; ++i)
#pragma unroll
                for (int j = 0; j < 8; ++j)
                    acc[i][j] = fmaf(ar[i], bc[j], acc[i][j]);
        }
        __syncthreads();
    }

    float4 bv0 = *(const float4*)&bias[n0 + tn * 4];
    float4 bv1 = *(const float4*)&bias[n0 + 64 + tn * 4];
    const float bb[8] = {bv0.x, bv0.y, bv0.z, bv0.w, bv1.x, bv1.y, bv1.z, bv1.w};
#pragma unroll
    for (int i = 0; i < 8; ++i) {
        const size_t rowoff = (size_t)(m0 + tm * 8 + i) * 512 + n0;
        float4 o0, o1;
        o0.x = acc[i][0] + bb[0]; o0.y = acc[i][1] + bb[1];
        o0.z = acc[i][2] + bb[2]; o0.w = acc[i][3] + bb[3];
        o1.x = acc[i][4] + bb[4]; o1.y = acc[i][5] + bb[5];
        o1.z = acc[i][6] + bb[6]; o1.w = acc[i][7] + bb[7];
        *(float4*)&C[rowoff + tn * 4] = o0;
        *(float4*)&C[rowoff + 64 + tn * 4] = o1;
    }
}

// ---------------------------------------------------------------------------
// Recurrent scan. Persistent cooperative kernel, grid = 256 WGs x 512 thr.
// Group = batch element b (64 groups); 4 slice-WGs per group; slice s owns
// output rows [128s, 128s+128) with W_hh slice pinned in VGPRs:
//   wave w (0..7), lane l: row = 128s + 16w + (l&15), k-span = [(l>>4)*128,+128)
//   -> 128 f32 of W per thread, forced resident via asm keepalive.
// Per step: poll tagged u64 h (skip own 128 rows: self-routed via LDS at
// publish), stage into parity-double-buffered LDS, ONE barrier, 128 FMA from
// registers + broadcast ds_read_b128, in-wave shfl_xor reduce (4 lanes/row),
// tanh, publish tagged u64 (relaxed agent atomics; no fences/cache ops).
// Parity double-buffer closes the overwrite race (proof as round 2/3).
// ---------------------------------------------------------------------------
__global__ __launch_bounds__(512, 2)
void rnn_scan(const float* __restrict__ proj, const float* __restrict__ Whh,
              const float* __restrict__ bhh, float* __restrict__ out,
              float* __restrict__ hidden, unsigned long long* __restrict__ hbuf)
{
    __shared__ float hS[2][528];   // [parity][512 + 4-float pad per 128]

    const int t   = threadIdx.x;
    const int bid = blockIdx.x;
    const int s   = bid >> 6;          // slice 0..3 (bid stride 64 -> same XCD)
    const int b   = bid & 63;          // batch element
    const int w   = t >> 6;            // wave 0..7
    const int l   = t & 63;
    const int lr  = l & 15;            // row-in-wave
    const int lc  = l >> 4;            // k-chunk 0..3
    const int row = s * 128 + w * 16 + lr;   // global output row

    // ---- one-time: W row-slice into VGPRs (forced resident) ----
    float Wr[128];
    {
        const float* wsrc = &Whh[(size_t)row * HID + lc * 128];
#pragma unroll
        for (int j = 0; j < 32; ++j) {
            float4 v = *(const float4*)&wsrc[j * 4];
            Wr[j * 4 + 0] = v.x; Wr[j * 4 + 1] = v.y;
            Wr[j * 4 + 2] = v.z; Wr[j * 4 + 3] = v.w;
        }
#pragma unroll
        for (int j = 0; j < 128; ++j) asm volatile("" : "+v"(Wr[j]));
    }
    const float breg = bhh[row];

    // init both LDS parities to h=0 (also covers step-0 self-routed slots)
    for (int i = t; i < 528; i += 512) { hS[0][i] = 0.f; hS[1][i] = 0.f; }
    __syncthreads();

    const bool own   = (t >> 7) == s;          // own k-range (self-routed)
    const int  pad_t = t + ((t >> 7) << 2);    // padded LDS index for k = t

    for (int step = 0; step < SEQ; ++step) {
        const int p = step & 1;

        // ---- proj prefetch (publisher lanes only) ----
        float pv = 0.f;
        size_t oidx = 0;
        if (lc == 0) {
            oidx = ((size_t)step * BATCH + b) * HID + row;
            pv = proj[oidx];
        }

        // ---- poll + stage non-own h (one tagged u64 per thread) ----
        if (!own) {
            const unsigned long long* src =
                hbuf + (size_t)p * (BATCH * HID) + (size_t)b * HID + t;
            const unsigned int want = (unsigned int)step;
            unsigned long long x;
            int spins = 0;
            for (;;) {
                x = __hip_atomic_load(src, __ATOMIC_RELAXED, __HIP_MEMORY_SCOPE_AGENT);
                if ((unsigned int)(x >> 32) == want) break;
                __builtin_amdgcn_s_sleep(1);
                if (++spins > 8192) {              // hang-proofing only
                    __builtin_amdgcn_fence(__ATOMIC_ACQUIRE, "agent");
                    spins = 0;
                }
            }
            hS[p][pad_t] = __uint_as_float((unsigned int)x);
        }
        __syncthreads();   // the ONLY barrier per step

        // ---- matvec: W in VGPRs, h broadcast from LDS (16-lane groups) ----
        const float* hp = &hS[p][lc * 132];
        float a0 = 0.f, a1 = 0.f, a2 = 0.f, a3 = 0.f;
#pragma unroll
        for (int j = 0; j < 32; j += 4) {
            float4 h0 = *(const float4*)&hp[(j + 0) * 4];
            float4 h1 = *(const float4*)&hp[(j + 1) * 4];
            float4 h2 = *(const float4*)&hp[(j + 2) * 4];
            float4 h3 = *(const float4*)&hp[(j + 3) * 4];
            a0 = fmaf(Wr[j*4+ 0], h0.x, a0); a0 = fmaf(Wr[j*4+ 1], h0.y, a0);
            a0 = fmaf(Wr[j*4+ 2], h0.z, a0); a0 = fmaf(Wr[j*4+ 3], h0.w, a0);
            a1 = fmaf(Wr[j*4+ 4], h1.x, a1); a1 = fmaf(Wr[j*4+ 5], h1.y, a1);
            a1 = fmaf(Wr[j*4+ 6], h1.z, a1); a1 = fmaf(Wr[j*4+ 7], h1.w, a1);
            a2 = fmaf(Wr[j*4+ 8], h2.x, a2); a2 = fmaf(Wr[j*4+ 9], h2.y, a2);
            a2 = fmaf(Wr[j*4+10], h2.z, a2); a2 = fmaf(Wr[j*4+11], h2.w, a2);
            a3 = fmaf(Wr[j*4+12], h3.x, a3); a3 = fmaf(Wr[j*4+13], h3.y, a3);
            a3 = fmaf(Wr[j*4+14], h3.z, a3); a3 = fmaf(Wr[j*4+15], h3.w, a3);
        }
        float sum = (a0 + a1) + (a2 + a3);
        // in-wave reduce across the 4 lanes sharing a row (l, l+16, l+32, l+48)
        sum += __shfl_xor(sum, 16, 64);
        sum += __shfl_xor(sum, 32, 64);

        // ---- tanh + publish (lanes lc==0), self-route next step's LDS ----
        if (lc == 0) {
            const float hn = tanhf(pv + breg + sum);
            out[oidx] = hn;
            const unsigned long long pk =
                ((unsigned long long)(unsigned int)(step + 1) << 32) |
                (unsigned long long)__float_as_uint(hn);
            __hip_atomic_store(
                &hbuf[(size_t)(p ^ 1) * (BATCH * HID) + (size_t)b * HID + row],
                pk, __ATOMIC_RELAXED, __HIP_MEMORY_SCOPE_AGENT);
            hS[p ^ 1][row + ((row >> 7) << 2)] = hn;   // self-route (own rows)
            if (step == SEQ - 1) hidden[(size_t)b * HID + row] = hn;
        }
        // no trailing barrier: next step's pre-barrier LDS writes touch only
        // parity p^1 slots disjoint from this step's hS[p] reads, and each
        // thread's own reads precede its next-step writes in program order.
    }
}

// ---------------------------------------------------------------------------
extern "C" void kernel_launch(void* const* d_in, const int* in_sizes, int n_in,
                              void* d_out, int out_size, void* d_ws, size_t ws_size,
                              hipStream_t stream)
{
    (void)in_sizes; (void)n_in; (void)out_size; (void)ws_size;

    const float* x    = (const float*)d_in[0];
    const float* Wih0 = (const float*)d_in[1];
    const float* Whh0 = (const float*)d_in[2];
    const float* bih0 = (const float*)d_in[3];
    const float* bhh0 = (const float*)d_in[4];
    const float* Wih1 = (const float*)d_in[5];
    const float* Whh1 = (const float*)d_in[6];
    const float* bih1 = (const float*)d_in[7];
    const float* bhh1 = (const float*)d_in[8];

    float* out1   = (float*)d_out;                        // [S][B][H]
    float* hidden = out1 + (size_t)SEQ * BATCH * HID;     // [2][B][H]

    float* proj = (float*)d_ws;                           // [S][B][H] f32
    unsigned long long* hbufA =
        (unsigned long long*)(proj + (size_t)SEQ * BATCH * HID);  // [2][B][H] u64
    unsigned long long* hbufB = hbufA + (size_t)2 * BATCH * HID;  // [2][B][H] u64

    // zero both layers' tagged h-state buffers (tag 0 == epoch 0, h = 0)
    hipMemsetAsync(hbufA, 0, (size_t)4 * BATCH * HID * sizeof(unsigned long long),
                   stream);

    // ---- layer 0 ----
    proj_gemm<<<dim3(4096), dim3(256), 0, stream>>>(x, Wih0, bih0, proj);
    {
        const float* p = proj; const float* w = Whh0; const float* bb = bhh0;
        float* o = out1; float* hd = hidden; unsigned long long* hb = hbufA;
        void* args[] = {&p, &w, &bb, &o, &hd, &hb};
        hipLaunchCooperativeKernel((const void*)rnn_scan, dim3(256), dim3(512),
                                   args, 0, stream);
    }

    // ---- layer 1 (out0 staged in d_out's out1 region) ----
    proj_gemm<<<dim3(4096), dim3(256), 0, stream>>>(out1, Wih1, bih1, proj);
    {
        const float* p = proj; const float* w = Whh1; const float* bb = bhh1;
        float* o = out1; float* hd = hidden + BATCH * HID; unsigned long long* hb = hbufB;
        void* args[] = {&p, &w, &bb, &o, &hd, &hb};
        hipLaunchCooperativeKernel((const void*)rnn_scan, dim3(256), dim3(512),
                                   args, 0, stream);
    }
}